// Round 3
// baseline (1042.246 us; speedup 1.0000x reference)
//
#include <hip/hip_runtime.h>
#include <stdint.h>

typedef short bf16x8 __attribute__((ext_vector_type(8)));
typedef float f32x4 __attribute__((ext_vector_type(4)));

__device__ __forceinline__ unsigned short f2bf(float f) {
  union { float f; unsigned int i; } v; v.f = f;
  unsigned int r = v.i + 0x7FFF + ((v.i >> 16) & 1);
  return (unsigned short)(r >> 16);
}
__device__ __forceinline__ void gload_lds16(const void* g, void* l) {
  __builtin_amdgcn_global_load_lds(
      (const __attribute__((address_space(1))) unsigned int*)g,
      (__attribute__((address_space(3))) unsigned int*)l,
      16, 0, 0);
}

// ---------------- convert f32 weights -> bf16 (Whh0, Wih1, Whh1, Wout) ----------------
__global__ __launch_bounds__(256) void k_cvt(const float* __restrict__ s0, const float* __restrict__ s1,
                                             const float* __restrict__ s2, const float* __restrict__ s3,
                                             unsigned short* __restrict__ d0, unsigned short* __restrict__ d1,
                                             unsigned short* __restrict__ d2, unsigned short* __restrict__ d3) {
  int j = blockIdx.x * 256 + threadIdx.x;   // 6656*256 = 1,703,936 vec8 jobs exactly
  const float* s; unsigned short* d; int o;
  if (j < 524288)       { s = s0; d = d0; o = j; }
  else if (j < 1048576) { s = s1; d = d1; o = j - 524288; }
  else if (j < 1572864) { s = s2; d = d2; o = j - 1048576; }
  else                  { s = s3; d = d3; o = j - 1572864; }
  size_t off = (size_t)o * 8;
  f32x4 v0 = *(const f32x4*)(s + off);
  f32x4 v1 = *(const f32x4*)(s + off + 4);
  bf16x8 r;
#pragma unroll
  for (int k = 0; k < 4; k++) { r[k] = (short)f2bf(v0[k]); r[4 + k] = (short)f2bf(v1[k]); }
  *(bf16x8*)(d + off) = r;
}

// ---------------- prep: embedding gather (f32) + zero state ----------------
__global__ __launch_bounds__(256) void k_prep(const int* __restrict__ ys,
                                              const float* __restrict__ embed,
                                              float* __restrict__ eys,
                                              float* __restrict__ h0h, float* __restrict__ h1h,
                                              float* __restrict__ c0, float* __restrict__ c1) {
  int idx = blockIdx.x * 256 + threadIdx.x;   // 16384 threads
  int row = idx >> 6;
  int e = (idx & 63) * 8;
  int y = ys[row];
  f32x4 v0 = {0.f, 0.f, 0.f, 0.f}, v1 = {0.f, 0.f, 0.f, 0.f};
  if (y != 0) {
    v0 = *(const f32x4*)(embed + (size_t)y * 512 + e);
    v1 = *(const f32x4*)(embed + (size_t)y * 512 + e + 4);
  }
  *(f32x4*)(eys + (size_t)row * 512 + e) = v0;
  *(f32x4*)(eys + (size_t)row * 512 + e + 4) = v1;
  if (idx < 4096) { h0h[idx] = 0.f; h1h[idx] = 0.f; }
  else if (idx < 8192) { c0[idx - 4096] = 0.f; c1[idx - 4096] = 0.f; }
}

// -------- generic small GEMM: C(f32 MxN) = A(f32 MxK) @ W(f32 NxK)^T + b1 + b2 --------
__global__ __launch_bounds__(256) void k_gemm_bias(const float* __restrict__ A,
                                                   const float* __restrict__ W,
                                                   const float* __restrict__ b1,
                                                   const float* __restrict__ b2,
                                                   float* __restrict__ C,
                                                   int M, int N, int K) {
  __shared__ unsigned short Als[64][40];
  __shared__ unsigned short Wls[64][40];
  int tid = threadIdx.x;
  int lane = tid & 63, wid = tid >> 6;
  int mtiles = M >> 6;
  int mt = blockIdx.x % mtiles, nt = blockIdx.x / mtiles;
  int srow = tid >> 2, sseg = tid & 3;
  f32x4 acc[4];
#pragma unroll
  for (int nf = 0; nf < 4; nf++) acc[nf] = (f32x4){0.f, 0.f, 0.f, 0.f};

  for (int kc = 0; kc < K; kc += 32) {
    const float* ap = A + (size_t)(mt * 64 + srow) * K + kc + sseg * 8;
    const float* wp = W + (size_t)(nt * 64 + srow) * K + kc + sseg * 8;
    f32x4 a0 = *(const f32x4*)ap, a1 = *(const f32x4*)(ap + 4);
    f32x4 w0 = *(const f32x4*)wp, w1 = *(const f32x4*)(wp + 4);
    bf16x8 av, wv;
#pragma unroll
    for (int k = 0; k < 4; k++) {
      av[k] = (short)f2bf(a0[k]); av[4 + k] = (short)f2bf(a1[k]);
      wv[k] = (short)f2bf(w0[k]); wv[4 + k] = (short)f2bf(w1[k]);
    }
    __syncthreads();
    *(bf16x8*)(&Als[srow][sseg * 8]) = av;
    *(bf16x8*)(&Wls[srow][sseg * 8]) = wv;
    __syncthreads();
    bf16x8 af = *(const bf16x8*)(&Als[wid * 16 + (lane & 15)][(lane >> 4) * 8]);
#pragma unroll
    for (int nf = 0; nf < 4; nf++) {
      bf16x8 bf = *(const bf16x8*)(&Wls[nf * 16 + (lane & 15)][(lane >> 4) * 8]);
      acc[nf] = __builtin_amdgcn_mfma_f32_16x16x32_bf16(af, bf, acc[nf], 0, 0, 0);
    }
  }
  int rloc = (lane >> 4) * 4;
  int col0 = lane & 15;
#pragma unroll
  for (int nf = 0; nf < 4; nf++) {
    int n = nt * 64 + nf * 16 + col0;
    float bias = 0.f;
    if (b1) bias += b1[n];
    if (b2) bias += b2[n];
#pragma unroll
    for (int r = 0; r < 4; r++) {
      int m = mt * 64 + wid * 16 + rloc + r;
      C[(size_t)m * N + n] = acc[nf][r] + bias;
    }
  }
}

// ---------------- LSTM pipelined phase: layer0 step p  ||  layer1 step p-1 -------------
// 256 blocks: 0..127 layer0 (8 channels each), 128..255 layer1. Weights pre-cvt to bf16.
__global__ __launch_bounds__(256) void k_lstm(int p,
    const float* __restrict__ X0,            // (B,U,4096)  eys@Wih0^T + bih0 + bhh0
    float* __restrict__ h0h,                 // (65,B,1024)
    float* __restrict__ h1h,                 // (65,B,1024)
    float* __restrict__ hdec,                // (B,U,1024) f32
    float* __restrict__ c0, float* __restrict__ c1,
    const unsigned short* __restrict__ W_hh0,
    const unsigned short* __restrict__ W_ih1,
    const unsigned short* __restrict__ W_hh1,
    const float* __restrict__ b_ih1,
    const float* __restrict__ b_hh1) {
  __shared__ float xs[2 * 4096];
  __shared__ float red[8][32][4];
  __shared__ float gsum[32][4];
  int tid = threadIdx.x;
  bool is1 = blockIdx.x >= 128;
  int base = (blockIdx.x & 127) * 8;

  if (!is1) {
    if (p >= 64) return;
    for (int i = tid; i < 1024; i += 256)
      ((f32x4*)xs)[i] = ((const f32x4*)(h0h + (size_t)p * 4096))[i];
  } else {
    if (p < 1) return;
    for (int i = tid; i < 1024; i += 256)
      ((f32x4*)xs)[i] = ((const f32x4*)(h0h + (size_t)p * 4096))[i];
    for (int i = tid; i < 1024; i += 256)
      ((f32x4*)(xs + 4096))[i] = ((const f32x4*)(h1h + (size_t)(p - 1) * 4096))[i];
  }
  __syncthreads();

  int s = tid >> 5;          // 0..7  K-segment
  int r = tid & 31;          // 0..31 row = g*8+cl
  int g = r >> 3, cl = r & 7;
  int wrow = g * 1024 + base + cl;

  const unsigned short* wptr;
  const float* xb;
  int nchunk;
  if (!is1) {
    wptr = W_hh0 + (size_t)wrow * 1024 + s * 128;
    xb = xs + s * 128;
    nchunk = 16;
  } else {
    if (s < 4) { wptr = W_ih1 + (size_t)wrow * 1024 + s * 256; xb = xs + s * 256; }
    else       { wptr = W_hh1 + (size_t)wrow * 1024 + (s - 4) * 256; xb = xs + 4096 + (s - 4) * 256; }
    nchunk = 32;
  }

  float a0 = 0.f, a1 = 0.f, a2 = 0.f, a3 = 0.f;
  for (int i = 0; i < nchunk; i++) {
    bf16x8 wv = *(const bf16x8*)(wptr + i * 8);
    f32x4 x00 = *(const f32x4*)(xb + i * 8);
    f32x4 x01 = *(const f32x4*)(xb + i * 8 + 4);
    f32x4 x10 = *(const f32x4*)(xb + 1024 + i * 8);
    f32x4 x11 = *(const f32x4*)(xb + 1024 + i * 8 + 4);
    f32x4 x20 = *(const f32x4*)(xb + 2048 + i * 8);
    f32x4 x21 = *(const f32x4*)(xb + 2048 + i * 8 + 4);
    f32x4 x30 = *(const f32x4*)(xb + 3072 + i * 8);
    f32x4 x31 = *(const f32x4*)(xb + 3072 + i * 8 + 4);
#pragma unroll
    for (int j = 0; j < 4; j++) {
      union { unsigned int i; float f; } wf; wf.i = ((unsigned int)(unsigned short)wv[j]) << 16;
      a0 += wf.f * x00[j]; a1 += wf.f * x10[j]; a2 += wf.f * x20[j]; a3 += wf.f * x30[j];
    }
#pragma unroll
    for (int j = 0; j < 4; j++) {
      union { unsigned int i; float f; } wf; wf.i = ((unsigned int)(unsigned short)wv[4 + j]) << 16;
      a0 += wf.f * x01[j]; a1 += wf.f * x11[j]; a2 += wf.f * x21[j]; a3 += wf.f * x31[j];
    }
  }
  *(f32x4*)&red[s][r][0] = (f32x4){a0, a1, a2, a3};
  __syncthreads();
  if (tid < 128) {
    int rr = tid >> 2, b = tid & 3;
    float sum = 0.f;
#pragma unroll
    for (int ss = 0; ss < 8; ss++) sum += red[ss][rr][b];
    gsum[rr][b] = sum;
  }
  __syncthreads();
  if (tid < 32) {
    int cl2 = tid >> 2, b = tid & 3;
    int ch = base + cl2;
    float gi = gsum[cl2][b], gf = gsum[8 + cl2][b], gg = gsum[16 + cl2][b], go = gsum[24 + cl2][b];
    if (!is1) {
      const float* x0p = X0 + ((size_t)(b * 64 + p)) * 4096;
      gi += x0p[ch]; gf += x0p[1024 + ch]; gg += x0p[2048 + ch]; go += x0p[3072 + ch];
      float* cp = c0 + b * 1024 + ch;
      float cold = *cp;
      float ii = 1.f / (1.f + __expf(-gi));
      float ff = 1.f / (1.f + __expf(-gf));
      float oo = 1.f / (1.f + __expf(-go));
      float cn = ff * cold + ii * tanhf(gg);
      *cp = cn;
      float hn = oo * tanhf(cn);
      h0h[(size_t)(p + 1) * 4096 + b * 1024 + ch] = hn;
    } else {
      int t1 = p - 1;
      gi += b_ih1[ch] + b_hh1[ch];
      gf += b_ih1[1024 + ch] + b_hh1[1024 + ch];
      gg += b_ih1[2048 + ch] + b_hh1[2048 + ch];
      go += b_ih1[3072 + ch] + b_hh1[3072 + ch];
      float* cp = c1 + b * 1024 + ch;
      float cold = *cp;
      float ii = 1.f / (1.f + __expf(-gi));
      float ff = 1.f / (1.f + __expf(-gf));
      float oo = 1.f / (1.f + __expf(-go));
      float cn = ff * cold + ii * tanhf(gg);
      *cp = cn;
      float hn = oo * tanhf(cn);
      h1h[(size_t)p * 4096 + b * 1024 + ch] = hn;
      hdec[((size_t)(b * 64 + t1)) * 1024 + ch] = hn;
    }
  }
}

// ---------------- joint: out[b,t,u,:] = tanh(encp[b,t,:]+decp[b,u,:]) @ Wout^T + bout ----
// 256 blocks x 512 threads. Block = 128-row M-tile (2 t-values x 64 u), z-panel in regs.
// OUTPUT IS FLOAT32.
__global__ __launch_bounds__(512) void k_joint(const float* __restrict__ encp,   // (B,T,512)
                                               const float* __restrict__ decp,   // (B,U,512)
                                               const unsigned short* __restrict__ Wout, // (2048,512) bf16
                                               const float* __restrict__ bout,   // (2048) f32
                                               float* __restrict__ out) {        // (B,T,U,2048) f32
  __shared__ unsigned short Wls[2][8192];   // 2 x 16KB: 128 n-rows x 64 k (swizzled)
  int tid = threadIdx.x;
  int lane = tid & 63, wid = tid >> 6;      // 8 waves
  int bidx = blockIdx.x;
  int b = bidx >> 6, tloc = bidx & 63;
  int t0 = tloc * 2;
  int wm = (wid >> 1) * 32;                 // 4 m-waves x 32 rows
  int wn = (wid & 1) * 64;                  // 2 n-waves x 64 cols

  // ---- prologue: issue stage of chunk 0 (overlaps with A-build) ----
  {
#pragma unroll
    for (int q = 0; q < 2; q++) {
      int idx = tid + q * 512;
      int n = idx >> 3, sl = idx & 7;
      int ss = sl ^ (n & 7);
      gload_lds16(Wout + (size_t)n * 512 + ss * 8, &Wls[0][idx * 8]);
    }
  }

  // ---- build A panel in registers: 2 m-frags x 16 k-frags, bf16x8 each ----
  bf16x8 afr[32];
#pragma unroll
  for (int mf = 0; mf < 2; mf++) {
    int r = wm + mf * 16 + (lane & 15);
    int t = t0 + (r >> 6), u = r & 63;
    const float* ep = encp + ((size_t)(b * 128 + t)) * 512;
    const float* dp = decp + ((size_t)(b * 64 + u)) * 512;
#pragma unroll
    for (int kf = 0; kf < 16; kf++) {
      int k0 = kf * 32 + ((lane >> 4) << 3);
      bf16x8 v;
#pragma unroll
      for (int j = 0; j < 8; j++) {
        float x = ep[k0 + j] + dp[k0 + j];
        float e = __expf(x + x);
        v[j] = (short)f2bf(1.f - 2.f / (e + 1.f));
      }
      afr[mf * 16 + kf] = v;
    }
  }

  f32x4 acc[2][4];
#pragma unroll
  for (int mf = 0; mf < 2; mf++)
#pragma unroll
    for (int nf = 0; nf < 4; nf++) acc[mf][nf] = (f32x4){0.f, 0.f, 0.f, 0.f};

  // ---- main loop: 16 n-tiles x 8 k-chunks, depth-1 prefetch ----
  for (int c = 0; c < 128; c++) {
    int nt = c >> 3, kc = c & 7;
    __syncthreads();                    // drains vmcnt(0): chunk c is in LDS
    if (c < 127) {
      int c1i = c + 1;
      int nn0 = (c1i >> 3) << 7;
      int kb = (c1i & 7) * 64;
      unsigned short* dst = Wls[c1i & 1];
#pragma unroll
      for (int q = 0; q < 2; q++) {
        int idx = tid + q * 512;
        int n = idx >> 3, sl = idx & 7;
        int ss = sl ^ (n & 7);
        gload_lds16(Wout + (size_t)(nn0 + n) * 512 + kb + ss * 8, dst + idx * 8);
      }
    }
    const unsigned short* Wb = Wls[c & 1];
#pragma unroll
    for (int ks = 0; ks < 2; ks++) {
      bf16x8 bfr[4];
#pragma unroll
      for (int nf = 0; nf < 4; nf++) {
        int n = wn + nf * 16 + (lane & 15);
        int slot = ks * 4 + (lane >> 4);
        int phys = slot ^ (n & 7);
        bfr[nf] = *(const bf16x8*)(Wb + n * 64 + phys * 8);
      }
      int kf = kc * 2 + ks;
#pragma unroll
      for (int mf = 0; mf < 2; mf++)
#pragma unroll
        for (int nf = 0; nf < 4; nf++)
          acc[mf][nf] = __builtin_amdgcn_mfma_f32_16x16x32_bf16(afr[mf * 16 + kf], bfr[nf],
                                                                acc[mf][nf], 0, 0, 0);
    }
    if (kc == 7) {                      // epilogue for this n-tile
      int n0 = nt << 7;
#pragma unroll
      for (int mf = 0; mf < 2; mf++) {
        int rb = wm + mf * 16 + ((lane >> 4) << 2);
#pragma unroll
        for (int nf = 0; nf < 4; nf++) {
          int o = n0 + wn + nf * 16 + (lane & 15);
          float bb = bout[o];
#pragma unroll
          for (int q = 0; q < 4; q++) {
            int rr = rb + q;
            int t = t0 + (rr >> 6), u = rr & 63;
            out[(((size_t)(b * 128 + t)) * 64 + u) * 2048 + o] = acc[mf][nf][q] + bb;
          }
          acc[mf][nf] = (f32x4){0.f, 0.f, 0.f, 0.f};
        }
      }
    }
  }
}

// ---------------- launch ----------------
extern "C" void kernel_launch(void* const* d_in, const int* in_sizes, int n_in,
                              void* d_out, int out_size, void* d_ws, size_t ws_size,
                              hipStream_t stream) {
  const float* hs   = (const float*)d_in[0];
  const int*   ys   = (const int*)d_in[1];
  const float* emb  = (const float*)d_in[2];
  const float* Wih0 = (const float*)d_in[3];
  const float* Whh0 = (const float*)d_in[4];
  const float* bih0 = (const float*)d_in[5];
  const float* bhh0 = (const float*)d_in[6];
  const float* Wih1 = (const float*)d_in[7];
  const float* Whh1 = (const float*)d_in[8];
  const float* bih1 = (const float*)d_in[9];
  const float* bhh1 = (const float*)d_in[10];
  const float* Wenc = (const float*)d_in[11];
  const float* benc = (const float*)d_in[12];
  const float* Wdec = (const float*)d_in[13];
  const float* Wout = (const float*)d_in[14];
  const float* bout = (const float*)d_in[15];

  char* ws = (char*)d_ws;
  float*          eys   = (float*)(ws + 0);            // 256x512 f32        = 524,288
  float*          X0    = (float*)(ws + 524288);       // 256x4096 f32       = 4,194,304
  float*          encp  = (float*)(ws + 4718592);      // 512x512 f32        = 1,048,576
  float*          decp  = (float*)(ws + 5767168);      // 256x512 f32        = 524,288
  float*          h0h   = (float*)(ws + 6291456);      // 65x4096 f32        = 1,064,960
  float*          h1h   = (float*)(ws + 7356416);      // 65x4096 f32        = 1,064,960
  float*          hdec  = (float*)(ws + 8421376);      // 256x1024 f32       = 1,048,576
  float*          c0    = (float*)(ws + 9469952);      // 4096 f32           = 16,384
  float*          c1    = (float*)(ws + 9486336);      // 4096 f32           = 16,384
  unsigned short* Whh0b = (unsigned short*)(ws + 9502720);   // 4M bf16      = 8,388,608
  unsigned short* Wih1b = (unsigned short*)(ws + 17891328);  // 4M bf16      = 8,388,608
  unsigned short* Whh1b = (unsigned short*)(ws + 26279936);  // 4M bf16      = 8,388,608
  unsigned short* Woutb = (unsigned short*)(ws + 34668544);  // 1M bf16      = 2,097,152
  float*          out   = (float*)d_out;                     // total ws = 36,765,696 B

  // weight conversion (bf16 for LSTM recurrent mats + Wout for global_load_lds)
  k_cvt<<<6656, 256, 0, stream>>>(Whh0, Wih1, Whh1, Wout, Whh0b, Wih1b, Whh1b, Woutb);
  k_prep<<<64, 256, 0, stream>>>(ys, emb, eys, h0h, h1h, c0, c1);
  // X0 = eys @ Wih0^T + bih0 + bhh0   (M=256, N=4096, K=512)
  k_gemm_bias<<<256, 256, 0, stream>>>(eys, Wih0, bih0, bhh0, X0, 256, 4096, 512);
  // encp = hs @ Wenc^T + benc         (M=512, N=512, K=512)
  k_gemm_bias<<<64, 256, 0, stream>>>(hs, Wenc, benc, nullptr, encp, 512, 512, 512);
  // LSTM: 65 pipelined phases
  for (int p = 0; p < 65; p++)
    k_lstm<<<256, 256, 0, stream>>>(p, X0, h0h, h1h, hdec, c0, c1,
                                    Whh0b, Wih1b, Whh1b, bih1, bhh1);
  // decp = hdec @ Wdec^T              (M=256, N=512, K=1024)
  k_gemm_bias<<<32, 256, 0, stream>>>(hdec, Wdec, nullptr, nullptr, decp, 256, 512, 1024);
  // joint
  k_joint<<<256, 512, 0, stream>>>(encp, decp, Woutb, bout, out);
}